// Round 7
// baseline (428.424 us; speedup 1.0000x reference)
//
#include <hip/hip_runtime.h>
#include <math.h>

#define NDIN 128
#define NHID 128
#define NDOUT 64

typedef _Float16 half2_t __attribute__((ext_vector_type(2)));
typedef _Float16 half4_t __attribute__((ext_vector_type(4)));
typedef _Float16 half8_t __attribute__((ext_vector_type(8)));
typedef float    float4v __attribute__((ext_vector_type(4)));

__device__ __forceinline__ float gelu_exact(float x) {
    return 0.5f * x * (1.0f + erff(x * 0.70710678118654752f));
}

// ---------------- prep0: 3x weight transpose+cast, zero count & done ----------------
// W[K][N] fp32 -> Wt[N][K] fp16, 32x32 LDS tiles.

__device__ void wtrans_tile(const float* __restrict__ W, _Float16* __restrict__ Wt,
                            int K, int N, int bx, int by) {
    __shared__ float tile[32][33];
    int tx = threadIdx.x & 31, ty = threadIdx.x >> 5;   // ty 0..7
    for (int i = 0; i < 32; i += 8) {
        int k = by * 32 + ty + i, nn = bx * 32 + tx;
        tile[ty + i][tx] = (k < K && nn < N) ? W[(size_t)k * N + nn] : 0.f;
    }
    __syncthreads();
    for (int i = 0; i < 32; i += 8) {
        int nn = bx * 32 + ty + i, k = by * 32 + tx;
        if (nn < N && k < K) Wt[(size_t)nn * K + k] = (_Float16)tile[tx][ty + i];
    }
}

// blocks: [0,16) W1; [16,32) W2; [32,40) W3; [40,40+NB) zero count (+done in block 40)
__global__ __launch_bounds__(256) void prep0_kernel(
    const float* __restrict__ W1, _Float16* __restrict__ W1t,
    const float* __restrict__ W2, _Float16* __restrict__ W2t,
    const float* __restrict__ W3, _Float16* __restrict__ W3t,
    int* __restrict__ count, int* __restrict__ done, int n) {
    int b = blockIdx.x;
    if (b < 16) {
        wtrans_tile(W1, W1t, NDIN, NHID, b & 3, b >> 2);
    } else if (b < 32) {
        wtrans_tile(W2, W2t, NHID, NHID, (b - 16) & 3, (b - 16) >> 2);
    } else if (b < 40) {
        wtrans_tile(W3, W3t, NHID, NDOUT, (b - 32) & 1, (b - 32) >> 1);
    } else {
        int z = b - 40;
        int i = z * 256 + threadIdx.x;
        if (i < n) count[i] = 0;
        if (z == 0 && threadIdx.x == 0) *done = 0;
    }
}

// ---------------- degree count ----------------

__global__ void count_kernel(const int* __restrict__ dst, int* __restrict__ count, int E) {
    int e = blockIdx.x * blockDim.x + threadIdx.x;
    if (e < E) atomicAdd(&count[dst[e]], 1);
}

// ---------------- fused per-block reduce + (last block) scan of partials ----------------
// atomics-only cross-block data path + threadfence: safe under XCD non-coherence.

__global__ __launch_bounds__(256) void reduce_scanp_kernel(
    const int* __restrict__ count, int* __restrict__ blocksum, int* __restrict__ blockoff,
    int* __restrict__ rowptr, int* __restrict__ done, int nb, int n) {
    __shared__ int s[256];
    __shared__ int islast;
    int t = threadIdx.x;
    int i = blockIdx.x * 256 + t;
    s[t] = (i < n) ? count[i] : 0;
    __syncthreads();
    for (int off = 128; off > 0; off >>= 1) {
        if (t < off) s[t] += s[t + off];
        __syncthreads();
    }
    if (t == 0) {
        atomicExch(&blocksum[blockIdx.x], s[0]);
        __threadfence();
        int old = atomicAdd(done, 1);
        islast = (old == nb - 1) ? 1 : 0;
    }
    __syncthreads();
    if (!islast) return;
    __threadfence();
    int v = (t < nb) ? atomicAdd(&blocksum[t], 0) : 0;
    s[t] = v;
    __syncthreads();
    for (int off = 1; off < 256; off <<= 1) {
        int u = (t >= off) ? s[t - off] : 0;
        __syncthreads();
        s[t] += u;
        __syncthreads();
    }
    if (t < nb) blockoff[t] = s[t] - v;   // exclusive
    if (t == 255) rowptr[n] = s[255];     // grand total (used by agg at node n-1)
}

// ---------------- per-segment scan + dinv ----------------

__global__ __launch_bounds__(256) void scan_blocks_kernel(
    const int* __restrict__ count, const int* __restrict__ blockoff,
    int* __restrict__ rowptr, float* __restrict__ dinv, int n) {
    __shared__ int s[256];
    int i = blockIdx.x * 256 + threadIdx.x;
    int v = (i < n) ? count[i] : 0;
    s[threadIdx.x] = v;
    __syncthreads();
    for (int off = 1; off < 256; off <<= 1) {
        int u = (threadIdx.x >= off) ? s[threadIdx.x - off] : 0;
        __syncthreads();
        s[threadIdx.x] += u;
        __syncthreads();
    }
    if (i < n) {
        rowptr[i] = blockoff[blockIdx.x] + s[threadIdx.x] - v;
        dinv[i] = rsqrtf((float)(v + 1));
    }
}

// ---------------- CSR fill (standalone: zero LDS -> full occupancy) ----------------

__global__ void fill_kernel(const int* __restrict__ src, const int* __restrict__ dst,
                            const float* __restrict__ dinv, const int* __restrict__ rowptr,
                            int* __restrict__ count, int2* __restrict__ adj, int E) {
    int e = blockIdx.x * blockDim.x + threadIdx.x;
    if (e >= E) return;
    int s = src[e], d = dst[e];
    int slot = atomicSub(&count[d], 1) - 1;
    int p = rowptr[d] + slot;
    adj[p] = make_int2(s, __float_as_int(dinv[s] * dinv[d]));
}

// ---------------- fp16 MFMA GEMM: T[M,BN] = A[M,128] @ Bt^T, fp16 out ----------------
// K fixed = 128, staged whole; 256 threads = 4 waves; wave w does rows [bm+16w,+16).
// NOTE: do NOT fuse no-LDS work into this kernel — its 52 KB static LDS would cap
// that work's occupancy at 3 blocks/CU (R5 regression: 16 -> 55 us).

template <int BN, bool AF16>
__global__ __launch_bounds__(256) void gemm_mfma(
    const void* __restrict__ Aptr, const _Float16* __restrict__ Bt,
    _Float16* __restrict__ T, int M) {
    __shared__ _Float16 lds_a[64][136];
    __shared__ _Float16 lds_bt[BN][136];
    const int K = 128;
    int tid = threadIdx.x;
    int bm = blockIdx.x * 64;
    int wave = tid >> 6, lane = tid & 63;
    int m = lane & 15, quad = lane >> 4;

    if (AF16) {
        const _Float16* A = (const _Float16*)Aptr;
#pragma unroll
        for (int j = 0; j < 4; j++) {
            int c = tid + j * 256;
            int r = c >> 4, col = (c & 15) << 3;
            int grow = bm + r;
            uint4 v = make_uint4(0, 0, 0, 0);
            if (grow < M) v = *(const uint4*)(A + (size_t)grow * K + col);
            *(uint4*)&lds_a[r][col] = v;
        }
    } else {
        const float* A = (const float*)Aptr;
#pragma unroll
        for (int j = 0; j < 8; j++) {
            int c = tid + j * 256;
            int r = c >> 5, col = (c & 31) << 2;
            int grow = bm + r;
            float4 v = make_float4(0.f, 0.f, 0.f, 0.f);
            if (grow < M) v = *(const float4*)(A + (size_t)grow * K + col);
            half4_t h;
            h[0] = (_Float16)v.x; h[1] = (_Float16)v.y;
            h[2] = (_Float16)v.z; h[3] = (_Float16)v.w;
            *(half4_t*)&lds_a[r][col] = h;
        }
    }
    {
        const int chunks = BN * K / 8;
        for (int c = tid; c < chunks; c += 256) {
            int r = c >> 4, col = (c & 15) << 3;
            *(uint4*)&lds_bt[r][col] = *(const uint4*)(Bt + (size_t)r * K + col);
        }
    }
    __syncthreads();

    const int NT = BN / 16;
    float4v acc[NT];
#pragma unroll
    for (int nt = 0; nt < NT; nt++) acc[nt] = (float4v){0.f, 0.f, 0.f, 0.f};

    int arow = (wave << 4) + m;
#pragma unroll
    for (int kc = 0; kc < K; kc += 32) {
        half8_t a = *(const half8_t*)&lds_a[arow][kc + quad * 8];
#pragma unroll
        for (int nt = 0; nt < NT; nt++) {
            half8_t b = *(const half8_t*)&lds_bt[nt * 16 + m][kc + quad * 8];
            acc[nt] = __builtin_amdgcn_mfma_f32_16x16x32_f16(a, b, acc[nt], 0, 0, 0);
        }
    }
#pragma unroll
    for (int nt = 0; nt < NT; nt++) {
#pragma unroll
        for (int r = 0; r < 4; r++) {
            int grow = bm + (wave << 4) + (quad << 2) + r;
            if (grow < M) T[(size_t)grow * BN + nt * 16 + m] = (_Float16)acc[nt][r];
        }
    }
}

// ---------------- aggregation, feature-sliced for per-XCD L2 residency ----------------
// out[i] = act( sum_e w_e*t[src_e] + dinv[i]^2*t[i] + b ), t fp16, fp32 accum.
// Block handles ONE feature slice (SF = F/NSLICE = 32 features = 64 B of each row).
// slice = blockIdx % NSLICE and (assumed) XCD = blockIdx % 8 => each XCD touches only
// one slice => gather working set F=128: 12.8/4 = 3.2 MB < 4 MB per-XCD L2.
// Wave = 16 groups x 4 lanes; each group gathers one edge's 64 B slice (16 B/lane),
// 1 KB per load instruction. Cross-group butterfly reduce at the end.
// If the %8 XCD mapping assumption is wrong this degrades to status quo, not breakage.

template <int F, int NSLICE, bool DOGELU, bool OUTF16>
__global__ __launch_bounds__(256) void agg_kernel(
    const _Float16* __restrict__ t, const int* __restrict__ rowptr,
    const int2* __restrict__ adj, const float* __restrict__ dinv,
    const float* __restrict__ bias, void* __restrict__ outp, int n) {
    constexpr int SF = F / NSLICE;               // 32 features per slice
    int slice = blockIdx.x % NSLICE;
    int node = (blockIdx.x / NSLICE) * 4 + (threadIdx.x >> 6);
    int lane = threadIdx.x & 63;
    if (node >= n) return;                       // wave-uniform exit

    int g = lane >> 2;                           // group 0..15
    int lsub = lane & 3;                         // lane in group
    int foff = slice * SF + lsub * 8;            // halves offset into row

    float acc[8];
#pragma unroll
    for (int f = 0; f < 8; f++) acc[f] = 0.f;

    float wself = dinv[node];
    wself *= wself;
    if (g == 0) {
        half8_t u = *(const half8_t*)(t + (size_t)node * F + foff);
#pragma unroll
        for (int f = 0; f < 8; f++) acc[f] = wself * (float)u[f];
    }

    int beg = rowptr[node];
    int end = rowptr[node + 1];
    for (int e0 = beg; e0 < end; e0 += 64) {
        int rem = end - e0;
        int j = 0; float w = 0.f;
        if (lane < rem) {
            int2 ed = adj[e0 + lane];
            j = ed.x; w = __int_as_float(ed.y);
        }
        int cnt = rem < 64 ? rem : 64;
        int iters = (cnt + 15) >> 4;             // <= 4
#pragma unroll 4
        for (int it = 0; it < iters; it++) {
            int srcl = (it << 4) + g;
            int jj = __shfl(j, srcl);            // group-uniform edge id
            float ww = __shfl(w, srcl);          // padded lanes: ww=0, jj=0 (row 0, cached)
            half8_t u = *(const half8_t*)(t + (size_t)jj * F + foff);
#pragma unroll
            for (int f = 0; f < 8; f++) acc[f] += ww * (float)u[f];
        }
    }
    // butterfly across the 16 groups (lanes with equal lsub hold the same features)
#pragma unroll
    for (int off = 4; off < 64; off <<= 1)
#pragma unroll
        for (int f = 0; f < 8; f++) acc[f] += __shfl_xor(acc[f], off);

    if (g == 0) {
        float4 b0 = *(const float4*)(bias + foff);
        float4 b1 = *(const float4*)(bias + foff + 4);
        acc[0] += b0.x; acc[1] += b0.y; acc[2] += b0.z; acc[3] += b0.w;
        acc[4] += b1.x; acc[5] += b1.y; acc[6] += b1.z; acc[7] += b1.w;
        if (DOGELU) {
#pragma unroll
            for (int f = 0; f < 8; f++) acc[f] = gelu_exact(acc[f]);
        }
        if (OUTF16) {
            half8_t o;
#pragma unroll
            for (int f = 0; f < 8; f++) o[f] = (_Float16)acc[f];
            *(half8_t*)((_Float16*)outp + (size_t)node * F + foff) = o;
        } else {
            float* op = (float*)outp + (size_t)node * F + foff;
            *(float4*)op = make_float4(acc[0], acc[1], acc[2], acc[3]);
            *(float4*)(op + 4) = make_float4(acc[4], acc[5], acc[6], acc[7]);
        }
    }
}

// ---------------- launch ----------------

extern "C" void kernel_launch(void* const* d_in, const int* in_sizes, int n_in,
                              void* d_out, int out_size, void* d_ws, size_t ws_size,
                              hipStream_t stream) {
    const float* x  = (const float*)d_in[0];
    const int* edge = (const int*)d_in[1];
    const float* W1 = (const float*)d_in[2];
    const float* b1 = (const float*)d_in[3];
    const float* W2 = (const float*)d_in[4];
    const float* b2 = (const float*)d_in[5];
    const float* W3 = (const float*)d_in[6];
    const float* b3 = (const float*)d_in[7];
    float* out = (float*)d_out;

    const int N = in_sizes[0] / NDIN;       // 50000
    const int E = in_sizes[1] / 2;          // 800000
    const int* src = edge;
    const int* dst = edge + E;
    const int NB = (N + 255) / 256;         // 196

    // workspace carve-out (256B aligned)
    char* p = (char*)d_ws;
    auto alloc = [&](size_t bytes) {
        char* q = p;
        p += (bytes + 255) & ~(size_t)255;
        return q;
    };
    int*       count    = (int*)alloc((size_t)N * 4);
    int*       rowptr   = (int*)alloc((size_t)(N + 1) * 4);
    int*       blocksum = (int*)alloc((size_t)NB * 4);
    int*       blockoff = (int*)alloc((size_t)NB * 4);
    int*       done     = (int*)alloc(256);
    float*     dinv     = (float*)alloc((size_t)N * 4);
    int2*      adj      = (int2*)alloc((size_t)E * 8);
    _Float16*  W1t      = (_Float16*)alloc((size_t)NHID * NDIN * 2);
    _Float16*  W2t      = (_Float16*)alloc((size_t)NHID * NHID * 2);
    _Float16*  W3t      = (_Float16*)alloc((size_t)NDOUT * NHID * 2);
    _Float16*  tbuf     = (_Float16*)alloc((size_t)N * NHID * 2);
    _Float16*  hbuf     = (_Float16*)alloc((size_t)N * NHID * 2);

    dim3 blk(256);
    int mtiles = (N + 63) / 64;             // 782
    int eblocks = (E + 255) / 256;          // 3125
    int ngroups = (N + 3) / 4;              // 12500 node-groups of 4
    int agg128_blocks = ngroups * 4;        // 4 feature slices
    int agg64_blocks  = ngroups * 2;        // 2 feature slices

    // 1. weight transpose+cast + zero count/done
    prep0_kernel<<<40 + NB, blk, 0, stream>>>(W1, W1t, W2, W2t, W3, W3t, count, done, N);
    // 2. degree count
    count_kernel<<<eblocks, blk, 0, stream>>>(dst, count, E);
    // 3. fused block-reduce + partial scan (last-block pattern)
    reduce_scanp_kernel<<<NB, blk, 0, stream>>>(count, blocksum, blockoff, rowptr,
                                                done, NB, N);
    // 4. per-segment scan + dinv
    scan_blocks_kernel<<<NB, blk, 0, stream>>>(count, blockoff, rowptr, dinv, N);
    // 5. CSR fill (no LDS, full occupancy)
    fill_kernel<<<eblocks, blk, 0, stream>>>(src, dst, dinv, rowptr, count, adj, E);
    // 6-11. gemm/agg chain
    gemm_mfma<128, false><<<mtiles, blk, 0, stream>>>(x, W1t, tbuf, N);
    agg_kernel<128, 4, true, true><<<agg128_blocks, blk, 0, stream>>>(
        tbuf, rowptr, adj, dinv, b1, hbuf, N);
    gemm_mfma<128, true><<<mtiles, blk, 0, stream>>>(hbuf, W2t, tbuf, N);
    agg_kernel<128, 4, true, true><<<agg128_blocks, blk, 0, stream>>>(
        tbuf, rowptr, adj, dinv, b2, hbuf, N);
    gemm_mfma<64, true><<<mtiles, blk, 0, stream>>>(hbuf, W3t, tbuf, N);
    agg_kernel<64, 2, false, false><<<agg64_blocks, blk, 0, stream>>>(
        tbuf, rowptr, adj, dinv, b3, out, N);
}

// Round 8
// 288.575 us; speedup vs baseline: 1.4846x; 1.4846x over previous
//
#include <hip/hip_runtime.h>
#include <math.h>

#define NDIN 128
#define NHID 128
#define NDOUT 64

typedef _Float16 half2_t __attribute__((ext_vector_type(2)));
typedef _Float16 half4_t __attribute__((ext_vector_type(4)));
typedef _Float16 half8_t __attribute__((ext_vector_type(8)));
typedef float    float4v __attribute__((ext_vector_type(4)));

__device__ __forceinline__ float gelu_exact(float x) {
    return 0.5f * x * (1.0f + erff(x * 0.70710678118654752f));
}

// ---------------- prep0: 3x weight transpose+cast, zero count & done ----------------
// W[K][N] fp32 -> Wt[N][K] fp16, 32x32 LDS tiles.

__device__ void wtrans_tile(const float* __restrict__ W, _Float16* __restrict__ Wt,
                            int K, int N, int bx, int by) {
    __shared__ float tile[32][33];
    int tx = threadIdx.x & 31, ty = threadIdx.x >> 5;   // ty 0..7
    for (int i = 0; i < 32; i += 8) {
        int k = by * 32 + ty + i, nn = bx * 32 + tx;
        tile[ty + i][tx] = (k < K && nn < N) ? W[(size_t)k * N + nn] : 0.f;
    }
    __syncthreads();
    for (int i = 0; i < 32; i += 8) {
        int nn = bx * 32 + ty + i, k = by * 32 + tx;
        if (nn < N && k < K) Wt[(size_t)nn * K + k] = (_Float16)tile[tx][ty + i];
    }
}

// blocks: [0,16) W1; [16,32) W2; [32,40) W3; [40,40+NB) zero count (+done in block 40)
__global__ __launch_bounds__(256) void prep0_kernel(
    const float* __restrict__ W1, _Float16* __restrict__ W1t,
    const float* __restrict__ W2, _Float16* __restrict__ W2t,
    const float* __restrict__ W3, _Float16* __restrict__ W3t,
    int* __restrict__ count, int* __restrict__ done, int n) {
    int b = blockIdx.x;
    if (b < 16) {
        wtrans_tile(W1, W1t, NDIN, NHID, b & 3, b >> 2);
    } else if (b < 32) {
        wtrans_tile(W2, W2t, NHID, NHID, (b - 16) & 3, (b - 16) >> 2);
    } else if (b < 40) {
        wtrans_tile(W3, W3t, NHID, NDOUT, (b - 32) & 1, (b - 32) >> 1);
    } else {
        int z = b - 40;
        int i = z * 256 + threadIdx.x;
        if (i < n) count[i] = 0;
        if (z == 0 && threadIdx.x == 0) *done = 0;
    }
}

// ---------------- degree count ----------------

__global__ void count_kernel(const int* __restrict__ dst, int* __restrict__ count, int E) {
    int e = blockIdx.x * blockDim.x + threadIdx.x;
    if (e < E) atomicAdd(&count[dst[e]], 1);
}

// ---------------- fused per-block reduce + (last block) scan of partials ----------------
// atomics-only cross-block data path + threadfence: safe under XCD non-coherence.

__global__ __launch_bounds__(256) void reduce_scanp_kernel(
    const int* __restrict__ count, int* __restrict__ blocksum, int* __restrict__ blockoff,
    int* __restrict__ rowptr, int* __restrict__ done, int nb, int n) {
    __shared__ int s[256];
    __shared__ int islast;
    int t = threadIdx.x;
    int i = blockIdx.x * 256 + t;
    s[t] = (i < n) ? count[i] : 0;
    __syncthreads();
    for (int off = 128; off > 0; off >>= 1) {
        if (t < off) s[t] += s[t + off];
        __syncthreads();
    }
    if (t == 0) {
        atomicExch(&blocksum[blockIdx.x], s[0]);
        __threadfence();
        int old = atomicAdd(done, 1);
        islast = (old == nb - 1) ? 1 : 0;
    }
    __syncthreads();
    if (!islast) return;
    __threadfence();
    int v = (t < nb) ? atomicAdd(&blocksum[t], 0) : 0;
    s[t] = v;
    __syncthreads();
    for (int off = 1; off < 256; off <<= 1) {
        int u = (t >= off) ? s[t - off] : 0;
        __syncthreads();
        s[t] += u;
        __syncthreads();
    }
    if (t < nb) blockoff[t] = s[t] - v;   // exclusive
    if (t == 255) rowptr[n] = s[255];     // grand total (used by agg at node n-1)
}

// ---------------- per-segment scan + dinv ----------------

__global__ __launch_bounds__(256) void scan_blocks_kernel(
    const int* __restrict__ count, const int* __restrict__ blockoff,
    int* __restrict__ rowptr, float* __restrict__ dinv, int n) {
    __shared__ int s[256];
    int i = blockIdx.x * 256 + threadIdx.x;
    int v = (i < n) ? count[i] : 0;
    s[threadIdx.x] = v;
    __syncthreads();
    for (int off = 1; off < 256; off <<= 1) {
        int u = (threadIdx.x >= off) ? s[threadIdx.x - off] : 0;
        __syncthreads();
        s[threadIdx.x] += u;
        __syncthreads();
    }
    if (i < n) {
        rowptr[i] = blockoff[blockIdx.x] + s[threadIdx.x] - v;
        dinv[i] = rsqrtf((float)(v + 1));
    }
}

// ---------------- CSR fill (standalone: zero LDS -> full occupancy) ----------------

__global__ void fill_kernel(const int* __restrict__ src, const int* __restrict__ dst,
                            const float* __restrict__ dinv, const int* __restrict__ rowptr,
                            int* __restrict__ count, int2* __restrict__ adj, int E) {
    int e = blockIdx.x * blockDim.x + threadIdx.x;
    if (e >= E) return;
    int s = src[e], d = dst[e];
    int slot = atomicSub(&count[d], 1) - 1;
    int p = rowptr[d] + slot;
    adj[p] = make_int2(s, __float_as_int(dinv[s] * dinv[d]));
}

// ---------------- fp16 MFMA GEMM: T[M,BN] = A[M,128] @ Bt^T, fp16 out ----------------
// K fixed = 128, staged whole; 256 threads = 4 waves; wave w does rows [bm+16w,+16).
// NOTE: do NOT fuse no-LDS work into this kernel — its 52 KB static LDS would cap
// that work's occupancy at 3 blocks/CU (R5 regression: 16 -> 55 us).

template <int BN, bool AF16>
__global__ __launch_bounds__(256) void gemm_mfma(
    const void* __restrict__ Aptr, const _Float16* __restrict__ Bt,
    _Float16* __restrict__ T, int M) {
    __shared__ _Float16 lds_a[64][136];
    __shared__ _Float16 lds_bt[BN][136];
    const int K = 128;
    int tid = threadIdx.x;
    int bm = blockIdx.x * 64;
    int wave = tid >> 6, lane = tid & 63;
    int m = lane & 15, quad = lane >> 4;

    if (AF16) {
        const _Float16* A = (const _Float16*)Aptr;
#pragma unroll
        for (int j = 0; j < 4; j++) {
            int c = tid + j * 256;
            int r = c >> 4, col = (c & 15) << 3;
            int grow = bm + r;
            uint4 v = make_uint4(0, 0, 0, 0);
            if (grow < M) v = *(const uint4*)(A + (size_t)grow * K + col);
            *(uint4*)&lds_a[r][col] = v;
        }
    } else {
        const float* A = (const float*)Aptr;
#pragma unroll
        for (int j = 0; j < 8; j++) {
            int c = tid + j * 256;
            int r = c >> 5, col = (c & 31) << 2;
            int grow = bm + r;
            float4 v = make_float4(0.f, 0.f, 0.f, 0.f);
            if (grow < M) v = *(const float4*)(A + (size_t)grow * K + col);
            half4_t h;
            h[0] = (_Float16)v.x; h[1] = (_Float16)v.y;
            h[2] = (_Float16)v.z; h[3] = (_Float16)v.w;
            *(half4_t*)&lds_a[r][col] = h;
        }
    }
    {
        const int chunks = BN * K / 8;
        for (int c = tid; c < chunks; c += 256) {
            int r = c >> 4, col = (c & 15) << 3;
            *(uint4*)&lds_bt[r][col] = *(const uint4*)(Bt + (size_t)r * K + col);
        }
    }
    __syncthreads();

    const int NT = BN / 16;
    float4v acc[NT];
#pragma unroll
    for (int nt = 0; nt < NT; nt++) acc[nt] = (float4v){0.f, 0.f, 0.f, 0.f};

    int arow = (wave << 4) + m;
#pragma unroll
    for (int kc = 0; kc < K; kc += 32) {
        half8_t a = *(const half8_t*)&lds_a[arow][kc + quad * 8];
#pragma unroll
        for (int nt = 0; nt < NT; nt++) {
            half8_t b = *(const half8_t*)&lds_bt[nt * 16 + m][kc + quad * 8];
            acc[nt] = __builtin_amdgcn_mfma_f32_16x16x32_f16(a, b, acc[nt], 0, 0, 0);
        }
    }
#pragma unroll
    for (int nt = 0; nt < NT; nt++) {
#pragma unroll
        for (int r = 0; r < 4; r++) {
            int grow = bm + (wave << 4) + (quad << 2) + r;
            if (grow < M) T[(size_t)grow * BN + nt * 16 + m] = (_Float16)acc[nt][r];
        }
    }
}

// ---------------- aggregation (R4 readlane formulation — best measured) ----------------
// out[i] = act( sum_e w_e*t[src_e] + dinv[i]^2*t[i] + b ); t fp16, fp32 accum.
// One wave per node. v_readlane with immediate lane -> SGPR-uniform gather base
// (scalar addressing, no ds_bpermute); 16 independent gathers in flight per chunk.
// NOTE (R6/R7): __shfl group-gather and feature-slicing variants both measured SLOWER
// (bpermute chains / 4x duplicated overhead); gather FETCH is at the XCD-replication
// compulsory floor (~94 MB fp16) served at ~3.2 TB/s — that is the structural limit.

template <int F, bool DOGELU, bool OUTF16>
__global__ __launch_bounds__(256) void agg_kernel(
    const _Float16* __restrict__ t, const int* __restrict__ rowptr,
    const int2* __restrict__ adj, const float* __restrict__ dinv,
    const float* __restrict__ bias, void* __restrict__ outp, int n) {
    int node = (int)((blockIdx.x * blockDim.x + threadIdx.x) >> 6);
    int lane = threadIdx.x & 63;
    if (node >= n) return;   // wave-uniform exit

    float wself = dinv[node];
    wself *= wself;
    int beg = rowptr[node];
    int end = rowptr[node + 1];

    if (F == 128) {
        const half2_t* t2 = (const half2_t*)t;
        half2_t v = t2[(size_t)node * 64 + lane];
        float accx = wself * (float)v[0], accy = wself * (float)v[1];
        for (int e0 = beg; e0 < end; e0 += 64) {
            int rem = end - e0;
            int j = 0; float w = 0.f;
            if (lane < rem) {
                int2 ed = adj[e0 + lane];
                j = ed.x; w = __int_as_float(ed.y);
            }
            int cnt = rem < 64 ? rem : 64;
            for (int c = 0; c < cnt; c += 16) {
#pragma unroll
                for (int i = 0; i < 16; i++) {
                    int jj = __builtin_amdgcn_readlane(j, c + i);
                    float ww = __int_as_float(
                        __builtin_amdgcn_readlane(__float_as_int(w), c + i));
                    half2_t u = t2[(size_t)jj * 64 + lane];
                    accx += ww * (float)u[0];
                    accy += ww * (float)u[1];
                }
            }
        }
        float2 b = ((const float2*)bias)[lane];
        accx += b.x; accy += b.y;
        if (DOGELU) { accx = gelu_exact(accx); accy = gelu_exact(accy); }
        if (OUTF16) {
            half2_t o; o[0] = (_Float16)accx; o[1] = (_Float16)accy;
            ((half2_t*)outp)[(size_t)node * 64 + lane] = o;
        } else {
            float2 o; o.x = accx; o.y = accy;
            ((float2*)outp)[(size_t)node * 64 + lane] = o;
        }
    } else {  // F == 64
        float acc = wself * (float)t[(size_t)node * 64 + lane];
        for (int e0 = beg; e0 < end; e0 += 64) {
            int rem = end - e0;
            int j = 0; float w = 0.f;
            if (lane < rem) {
                int2 ed = adj[e0 + lane];
                j = ed.x; w = __int_as_float(ed.y);
            }
            int cnt = rem < 64 ? rem : 64;
            for (int c = 0; c < cnt; c += 16) {
#pragma unroll
                for (int i = 0; i < 16; i++) {
                    int jj = __builtin_amdgcn_readlane(j, c + i);
                    float ww = __int_as_float(
                        __builtin_amdgcn_readlane(__float_as_int(w), c + i));
                    acc += ww * (float)t[(size_t)jj * 64 + lane];
                }
            }
        }
        acc += bias[lane];
        if (DOGELU) acc = gelu_exact(acc);
        if (OUTF16) ((_Float16*)outp)[(size_t)node * 64 + lane] = (_Float16)acc;
        else        ((float*)outp)[(size_t)node * 64 + lane] = acc;
    }
}

// ---------------- launch ----------------

extern "C" void kernel_launch(void* const* d_in, const int* in_sizes, int n_in,
                              void* d_out, int out_size, void* d_ws, size_t ws_size,
                              hipStream_t stream) {
    const float* x  = (const float*)d_in[0];
    const int* edge = (const int*)d_in[1];
    const float* W1 = (const float*)d_in[2];
    const float* b1 = (const float*)d_in[3];
    const float* W2 = (const float*)d_in[4];
    const float* b2 = (const float*)d_in[5];
    const float* W3 = (const float*)d_in[6];
    const float* b3 = (const float*)d_in[7];
    float* out = (float*)d_out;

    const int N = in_sizes[0] / NDIN;       // 50000
    const int E = in_sizes[1] / 2;          // 800000
    const int* src = edge;
    const int* dst = edge + E;
    const int NB = (N + 255) / 256;         // 196

    // workspace carve-out (256B aligned)
    char* p = (char*)d_ws;
    auto alloc = [&](size_t bytes) {
        char* q = p;
        p += (bytes + 255) & ~(size_t)255;
        return q;
    };
    int*       count    = (int*)alloc((size_t)N * 4);
    int*       rowptr   = (int*)alloc((size_t)(N + 1) * 4);
    int*       blocksum = (int*)alloc((size_t)NB * 4);
    int*       blockoff = (int*)alloc((size_t)NB * 4);
    int*       done     = (int*)alloc(256);
    float*     dinv     = (float*)alloc((size_t)N * 4);
    int2*      adj      = (int2*)alloc((size_t)E * 8);
    _Float16*  W1t      = (_Float16*)alloc((size_t)NHID * NDIN * 2);
    _Float16*  W2t      = (_Float16*)alloc((size_t)NHID * NHID * 2);
    _Float16*  W3t      = (_Float16*)alloc((size_t)NDOUT * NHID * 2);
    _Float16*  tbuf     = (_Float16*)alloc((size_t)N * NHID * 2);
    _Float16*  hbuf     = (_Float16*)alloc((size_t)N * NHID * 2);

    dim3 blk(256);
    int mtiles = (N + 63) / 64;             // 782
    int eblocks = (E + 255) / 256;          // 3125
    int agg_blocks = (N + 3) / 4;           // 12500 (4 waves/block, 1 node/wave)

    // 1. weight transpose+cast + zero count/done
    prep0_kernel<<<40 + NB, blk, 0, stream>>>(W1, W1t, W2, W2t, W3, W3t, count, done, N);
    // 2. degree count
    count_kernel<<<eblocks, blk, 0, stream>>>(dst, count, E);
    // 3. fused block-reduce + partial scan (last-block pattern)
    reduce_scanp_kernel<<<NB, blk, 0, stream>>>(count, blocksum, blockoff, rowptr,
                                                done, NB, N);
    // 4. per-segment scan + dinv
    scan_blocks_kernel<<<NB, blk, 0, stream>>>(count, blockoff, rowptr, dinv, N);
    // 5. CSR fill (no LDS, full occupancy)
    fill_kernel<<<eblocks, blk, 0, stream>>>(src, dst, dinv, rowptr, count, adj, E);
    // 6-11. gemm/agg chain
    gemm_mfma<128, false><<<mtiles, blk, 0, stream>>>(x, W1t, tbuf, N);
    agg_kernel<128, true, true><<<agg_blocks, blk, 0, stream>>>(tbuf, rowptr, adj,
                                                                dinv, b1, hbuf, N);
    gemm_mfma<128, true><<<mtiles, blk, 0, stream>>>(hbuf, W2t, tbuf, N);
    agg_kernel<128, true, true><<<agg_blocks, blk, 0, stream>>>(tbuf, rowptr, adj,
                                                                dinv, b2, hbuf, N);
    gemm_mfma<64, true><<<mtiles, blk, 0, stream>>>(hbuf, W3t, tbuf, N);
    agg_kernel<64, false, false><<<agg_blocks, blk, 0, stream>>>(tbuf, rowptr, adj,
                                                                 dinv, b3, out, N);
}